// Round 1
// baseline (296.962 us; speedup 1.0000x reference)
//
#include <hip/hip_runtime.h>
#include <math.h>

#define HN       250
#define WN       400
#define N_RAYS   (HN * WN)        // 100000
#define N_SAMP   1000000
#define P_TENSO  50000
#define STEP_SZ  0.005f
#define DENS_SCALE 1.0f           // min(1/(1-0), 25) = 1
#define NB_SCAN  ((P_TENSO + 1023) / 1024)   // 49

// NOTE (R7): cooperative grid.sync() measured ~100 us/sync on MI355X — do not
// re-fuse with cooperative launch. NOTE (R8): each device-scope returning
// atomicAdd costs a 64B line transaction (1M atomics == 64 MB WRITE_SIZE);
// the atomic pass, not the payload writes, dominates scatter-type kernels.
// NOTE (R9, this round): perm/iperm indirection removed — data is physically
// permuted once (scatter STORES) so gather and ray_render read sequentially.
// Random loads -> random stores: latency-critical chains eliminated.

// ---------------- workspace layout (bytes) ----------------
#define OFF_SORT    0            // 1M x 32B sample structs, SORTED (pos) order
#define OFF_RESULTS 32000000     // 1M x 16B (lt,r,g,b), ORIGINAL (n) order
#define OFF_RANK    48000000     // 1M int, rank within tid
#define OFF_CURSOR  52000000     // 50K int (atomic counters == final counts)
#define OFF_STARTS  52200000     // 50K int
#define OFF_BSUMS   52400000     // 64 int
#define OFF_FLAG    52400512     // 1 int (spin-barrier arrival)
#define OFF_RSTART  52401024     // (N_RAYS+1) int
#define WS_NEED     (52401024 + 400004 + 64)

// gather slab layout (floats), per wave
#define ROW_STRIDE 20                 // 16 ch + 4 pad
#define TV_F   (24 * ROW_STRIDE)      // 480
#define SLAB_F (TV_F + 16 + 48)       // 544

// ---------------------------------------------------------------------------
// A: rank via ONE returning atomic pass + ray bounds. No payload packing here
// (R9): build_sorted re-reads raw inputs, so A is atomic+bounds only.
// ---------------------------------------------------------------------------
__global__ __launch_bounds__(256) void count_bounds_rank(
    const int* __restrict__ tenso_id,
    const int* __restrict__ ray_id,     // sorted
    int* __restrict__ cursor,           // zeroed; becomes counts
    int* __restrict__ rank,
    int* __restrict__ ray_start)
{
    int n = blockIdx.x * 256 + threadIdx.x;
    if (n >= N_SAMP) return;

    rank[n] = atomicAdd(&cursor[tenso_id[n]], 1);  // the single atomic pass

    int r = ray_id[n];
    int rprev = (n == 0) ? -1 : ray_id[n - 1];
    for (int q = rprev + 1; q <= r; ++q) ray_start[q] = n;
    if (n == N_SAMP - 1) {
        for (int q = r + 1; q <= N_RAYS; ++q) ray_start[q] = N_SAMP;
    }
}

// ---------------------------------------------------------------------------
// B: fused exclusive scan of counts -> starts. 49 blocks (co-resident on 256
// CUs), internal spin barrier on an arrival counter.
// ---------------------------------------------------------------------------
__global__ __launch_bounds__(256) void scan_fused(
    const int* __restrict__ cursor,   // counts
    int* __restrict__ starts,
    int* __restrict__ bsums,
    int* __restrict__ flag)
{
    __shared__ int lds[257];
    const int b = blockIdx.x;
    const int t = threadIdx.x;
    const int base = b * 1024 + t * 4;

    int v[4]; int s = 0;
    #pragma unroll
    for (int i = 0; i < 4; ++i) {
        int idx = base + i;
        v[i] = (idx < P_TENSO) ? cursor[idx] : 0;
        s += v[i];
    }
    lds[t] = s;
    __syncthreads();
    for (int d = 1; d < 256; d <<= 1) {
        int x = (t >= d) ? lds[t - d] : 0;
        __syncthreads();
        lds[t] += x;
        __syncthreads();
    }
    if (t == 255) bsums[b] = lds[255];

    // ---- barrier across the 49 blocks ----
    __threadfence();
    __syncthreads();
    if (t == 0) {
        atomicAdd(flag, 1);
        while (atomicAdd(flag, 0) < gridDim.x) { }
    }
    __syncthreads();
    __threadfence();

    // every block computes its global prefix = sum of bsums[0..b)
    if (t < 64) {
        int x = (t < b) ? bsums[t] : 0;
        #pragma unroll
        for (int m = 1; m < 64; m <<= 1) x += __shfl_xor(x, m);
        if (t == 0) lds[256] = x;
    }
    __syncthreads();
    const int pre = lds[256];

    int run = pre + ((t > 0) ? lds[t - 1] : 0);
    #pragma unroll
    for (int i = 0; i < 4; ++i) {
        int idx = base + i;
        if (idx < P_TENSO) starts[idx] = run;
        run += v[i];
    }
}

// ---------------------------------------------------------------------------
// C: build the physically-sorted sample array. Coalesced reads of the raw
// inputs (n order), scattered 32B writes to pos order. Original index n is
// stowed in B.w so gather can scatter results back to original order.
// ---------------------------------------------------------------------------
__global__ __launch_bounds__(256) void build_sorted(
    const int*   __restrict__ tenso_id,
    const int*   __restrict__ rank,
    const int*   __restrict__ starts,
    const int*   __restrict__ gis, const int* __restrict__ gil,
    const float* __restrict__ gws, const float* __restrict__ gwl,
    float4* __restrict__ sorted)
{
    int n = blockIdx.x * 256 + threadIdx.x;
    if (n >= N_SAMP) return;

    const int pos = starts[tenso_id[n]] + rank[n];

    unsigned bits = (unsigned)gis[n*3+0] | ((unsigned)gis[n*3+1] << 3) | ((unsigned)gis[n*3+2] << 6)
                  | ((unsigned)gil[n*3+0] << 9) | ((unsigned)gil[n*3+1] << 12) | ((unsigned)gil[n*3+2] << 15);
    float4 A = make_float4(gws[n*3+0], gws[n*3+1], gws[n*3+2], gwl[n*3+0]);
    float4 B = make_float4(gwl[n*3+1], gwl[n*3+2], __uint_as_float(bits),
                           __uint_as_float((unsigned)n));
    sorted[(size_t)pos * 2 + 0] = A;   // scattered 32B store (latency-tolerant)
    sorted[(size_t)pos * 2 + 1] = B;
}

// ---------------------------------------------------------------------------
// Gather: one wave per tensoRF id; lanes = 16 samples x 4 channel-groups.
// R9: reads sorted[] sequentially (no perm load, no random load, no dependent
// chain); writes results to ORIGINAL order (scatter store) so ray_render
// streams.
// ---------------------------------------------------------------------------
__global__ __launch_bounds__(256) void gather_phase(
    const float* __restrict__ trivecs,   // (P,16,3,8)
    const float* __restrict__ densities, // (P,16)
    const float* __restrict__ colors,    // (P,16,3)
    const int*   __restrict__ starts,
    const int*   __restrict__ counts,    // == cursor
    const float4* __restrict__ sorted,
    float* __restrict__ results_f)       // [n*4 + j], original order
{
    __shared__ __align__(16) float lds[4 * SLAB_F];
    const int lane = threadIdx.x & 63;
    const int wv   = threadIdx.x >> 6;
    const int t    = blockIdx.x * 4 + wv;
    if (t >= P_TENSO) return;

    const int start = starts[t];
    const int cnt   = counts[t];
    if (cnt == 0) return;

    float* slab = lds + wv * SLAB_F;
    float* dl   = slab + TV_F;
    float* cl   = dl + 16;

    const float* tvg = trivecs + (size_t)t * 384;
    #pragma unroll
    for (int i = 0; i < 6; ++i) {
        int l = lane + i * 64;
        int c = l / 24;
        int rem = l - c * 24;
        slab[rem * ROW_STRIDE + c] = tvg[l];
    }
    if (lane < 16) dl[lane] = densities[(size_t)t * 16 + lane];
    if (lane < 48) {
        int c = lane / 3, k = lane - c * 3;
        cl[k * 16 + c] = colors[(size_t)t * 48 + lane];
    }

    const int g = lane >> 2;   // sample slot 0..15
    const int j = lane & 3;    // channel group

    const float4 dens4 = *(const float4*)(dl + 4 * j);
    const float4 col0  = *(const float4*)(cl + 4 * j);
    const float4 col1  = *(const float4*)(cl + 16 + 4 * j);
    const float4 col2  = *(const float4*)(cl + 32 + 4 * j);

    const int end = start + cnt;
    const int niter = (cnt + 15) >> 4;

    for (int it = 0; it < niter; ++it) {
        const int pos = start + it * 16 + g;
        const bool valid = (pos < end);
        const int cp = valid ? pos : (end - 1);
        const float4 A = sorted[(size_t)cp * 2 + 0];   // coalesced, quad-bcast
        const float4 B = sorted[(size_t)cp * 2 + 1];
        const unsigned bits = __float_as_uint(B.z);
        const unsigned n    = __float_as_uint(B.w);

        float4 f;
        {
            const int is = bits & 7, il = (bits >> 9) & 7;
            const float4 vs = *(const float4*)(slab + is * ROW_STRIDE + 4 * j);
            const float4 vl = *(const float4*)(slab + il * ROW_STRIDE + 4 * j);
            f.x = vs.x * A.x + vl.x * A.w;
            f.y = vs.y * A.x + vl.y * A.w;
            f.z = vs.z * A.x + vl.z * A.w;
            f.w = vs.w * A.x + vl.w * A.w;
        }
        {
            const int is = (bits >> 3) & 7, il = (bits >> 12) & 7;
            const float4 vs = *(const float4*)(slab + (8 + is) * ROW_STRIDE + 4 * j);
            const float4 vl = *(const float4*)(slab + (8 + il) * ROW_STRIDE + 4 * j);
            f.x *= vs.x * A.y + vl.x * B.x;
            f.y *= vs.y * A.y + vl.y * B.x;
            f.z *= vs.z * A.y + vl.z * B.x;
            f.w *= vs.w * A.y + vl.w * B.x;
        }
        {
            const int is = (bits >> 6) & 7, il = (bits >> 15) & 7;
            const float4 vs = *(const float4*)(slab + (16 + is) * ROW_STRIDE + 4 * j);
            const float4 vl = *(const float4*)(slab + (16 + il) * ROW_STRIDE + 4 * j);
            f.x *= vs.x * A.z + vl.x * B.y;
            f.y *= vs.y * A.z + vl.y * B.y;
            f.z *= vs.z * A.z + vl.z * B.y;
            f.w *= vs.w * A.z + vl.w * B.y;
        }

        float s0 = f.x * dens4.x + f.y * dens4.y + f.z * dens4.z + f.w * dens4.w;
        float s1 = f.x * col0.x  + f.y * col0.y  + f.z * col0.z  + f.w * col0.w;
        float s2 = f.x * col1.x  + f.y * col1.y  + f.z * col1.z  + f.w * col1.w;
        float s3 = f.x * col2.x  + f.y * col2.y  + f.z * col2.z  + f.w * col2.w;

        s0 += __shfl_xor(s0, 1); s0 += __shfl_xor(s0, 2);
        s1 += __shfl_xor(s1, 1); s1 += __shfl_xor(s1, 2);
        s2 += __shfl_xor(s2, 1); s2 += __shfl_xor(s2, 2);
        s3 += __shfl_xor(s3, 1); s3 += __shfl_xor(s3, 2);

        const float sj = (j == 0) ? s0 : (j == 1) ? s1 : (j == 2) ? s2 : s3;
        float val;
        if (j == 0) {
            float dens = fmaxf(sj, 0.0f) + __logf(1.0f + __expf(-fabsf(sj)));
            val = -(dens * DENS_SCALE) * STEP_SZ;            // lt
        } else {
            val = 1.0f / (1.0f + __expf(-sj));               // sigmoid
        }
        if (valid) results_f[(size_t)n * 4 + j] = val;       // 16B scatter store
    }
}

// ---------------------------------------------------------------------------
// E: one thread per ray; sequential recurrence. R9: results are in original
// (n) order -> purely streaming loads, no indirection.
// ---------------------------------------------------------------------------
__global__ __launch_bounds__(256) void ray_render(
    const float4* __restrict__ results,
    const float*  __restrict__ t_min,
    const float*  __restrict__ bg,
    const int*    __restrict__ ray_start,
    const int*    __restrict__ step_id,
    float* __restrict__ out)
{
    int r = blockIdx.x * 256 + threadIdx.x;
    if (r >= N_RAYS) return;
    const int s = ray_start[r];
    const int e = ray_start[r + 1];
    const float tmin_r = t_min[r];

    float T = 0.0f, aR = 0.0f, aG = 0.0f, aB = 0.0f, aD = 0.0f;
    for (int n = s; n < e; ++n) {
        float4 res = results[n];
        const float lt = res.x;
        const float w = (1.0f - __expf(lt)) * __expf(T);
        T += lt;
        const float z = tmin_r + (float)step_id[n] * STEP_SZ;
        aR += w * res.y;
        aG += w * res.z;
        aB += w * res.w;
        aD += w * z;
    }
    const float bgw = __expf(T);
    out[0 * N_RAYS + r] = aR + bgw * bg[0];
    out[1 * N_RAYS + r] = aG + bgw * bg[1];
    out[2 * N_RAYS + r] = aB + bgw * bg[2];
    out[3 * N_RAYS + r] = aD;
    out[4 * N_RAYS + r] = 1.0f - bgw;
}

// ---------------------------------------------------------------------------
// Fallback (ws too small): single fused kernel, original layouts.
// ---------------------------------------------------------------------------
__global__ __launch_bounds__(256) void trivec_render_fallback(
    const float* __restrict__ trivecs, const float* __restrict__ densities,
    const float* __restrict__ colors, const float* __restrict__ gws,
    const float* __restrict__ gwl, const float* __restrict__ t_min,
    const float* __restrict__ bg, const int* __restrict__ gis,
    const int* __restrict__ gil, const int* __restrict__ tenso_id,
    const int* __restrict__ ray_id, const int* __restrict__ step_id,
    float* __restrict__ out)
{
    const int lane = threadIdx.x & 63;
    const int r = blockIdx.x * 4 + (threadIdx.x >> 6);
    if (r >= N_RAYS) return;
    const int c = lane & 15;
    const int g = lane >> 4;
    int lo = 0, hi = N_SAMP;
    while (lo < hi) { int mid = (lo + hi) >> 1; if (ray_id[mid] < r) lo = mid + 1; else hi = mid; }
    const int seg_start = lo;
    hi = N_SAMP;
    while (lo < hi) { int mid = (lo + hi) >> 1; if (ray_id[mid] < r + 1) lo = mid + 1; else hi = mid; }
    const int seg_end = lo;
    const float tmin_r = t_min[r];
    float Tlog = 0.0f, accR = 0.0f, accG = 0.0f, accB = 0.0f, accD = 0.0f;
    const int niter = (seg_end - seg_start + 3) >> 2;
    for (int it = 0; it < niter; ++it) {
        const int n = seg_start + it * 4 + g;
        const bool valid = (n < seg_end);
        const int nc = valid ? n : (seg_end - 1);
        const int tid = tenso_id[nc];
        const float* tv = trivecs + (size_t)tid * 384 + c * 24;
        float f = 1.0f;
        #pragma unroll
        for (int a = 0; a < 3; ++a) {
            const int is = gis[nc*3+a], il = gil[nc*3+a];
            const float wS = gws[nc*3+a], wL = gwl[nc*3+a];
            f *= (tv[a*8+is] * wS + tv[a*8+il] * wL);
        }
        const float dns = densities[(size_t)tid * 16 + c];
        const float* colp = colors + ((size_t)tid * 16 + c) * 3;
        float s0 = f*dns, s1 = f*colp[0], s2 = f*colp[1], s3 = f*colp[2];
        #pragma unroll
        for (int m = 1; m < 16; m <<= 1) {
            s0 += __shfl_xor(s0, m); s1 += __shfl_xor(s1, m);
            s2 += __shfl_xor(s2, m); s3 += __shfl_xor(s3, m);
        }
        float dens = fmaxf(s0, 0.0f) + __logf(1.0f + __expf(-fabsf(s0)));
        const float lt = valid ? (-dens * STEP_SZ) : 0.0f;
        const float alpha = 1.0f - __expf(lt);
        const float rr = 1.0f/(1.0f+__expf(-s1)), gg = 1.0f/(1.0f+__expf(-s2)), bb = 1.0f/(1.0f+__expf(-s3));
        const float z = tmin_r + (float)step_id[nc] * STEP_SZ;
        const float lt0 = __shfl(lt,0), lt1 = __shfl(lt,16), lt2 = __shfl(lt,32), lt3 = __shfl(lt,48);
        float excl = Tlog;
        if (g > 0) excl += lt0;
        if (g > 1) excl += lt1;
        if (g > 2) excl += lt2;
        const float w = alpha * __expf(excl);
        Tlog += lt0 + lt1 + lt2 + lt3;
        accR += w*rr; accG += w*gg; accB += w*bb; accD += w*z;
    }
    accR += __shfl_xor(accR,16); accR += __shfl_xor(accR,32);
    accG += __shfl_xor(accG,16); accG += __shfl_xor(accG,32);
    accB += __shfl_xor(accB,16); accB += __shfl_xor(accB,32);
    accD += __shfl_xor(accD,16); accD += __shfl_xor(accD,32);
    const float bgw = __expf(Tlog);
    if (lane == 0) {
        out[0*N_RAYS+r] = accR + bgw*bg[0];
        out[1*N_RAYS+r] = accG + bgw*bg[1];
        out[2*N_RAYS+r] = accB + bgw*bg[2];
        out[3*N_RAYS+r] = accD;
        out[4*N_RAYS+r] = 1.0f - bgw;
    }
}

extern "C" void kernel_launch(void* const* d_in, const int* in_sizes, int n_in,
                              void* d_out, int out_size, void* d_ws, size_t ws_size,
                              hipStream_t stream) {
    const float* trivecs   = (const float*)d_in[0];
    const float* densities = (const float*)d_in[1];
    const float* colors    = (const float*)d_in[2];
    const float* gws       = (const float*)d_in[3];
    const float* gwl       = (const float*)d_in[4];
    const float* t_min     = (const float*)d_in[5];
    const float* bg        = (const float*)d_in[6];
    const int*   gis       = (const int*)d_in[7];
    const int*   gil       = (const int*)d_in[8];
    const int*   tenso_id  = (const int*)d_in[9];
    const int*   ray_id    = (const int*)d_in[10];
    const int*   step_id   = (const int*)d_in[11];
    float* out = (float*)d_out;

    if (ws_size < (size_t)WS_NEED) {
        trivec_render_fallback<<<(N_RAYS + 3) / 4, 256, 0, stream>>>(
            trivecs, densities, colors, gws, gwl, t_min, bg,
            gis, gil, tenso_id, ray_id, step_id, out);
        return;
    }

    char* ws = (char*)d_ws;
    float4* sorted   = (float4*)(ws + OFF_SORT);
    float4* results  = (float4*)(ws + OFF_RESULTS);
    int*    rank     = (int*)(ws + OFF_RANK);
    int*    cursor   = (int*)(ws + OFF_CURSOR);
    int*    starts   = (int*)(ws + OFF_STARTS);
    int*    bsums    = (int*)(ws + OFF_BSUMS);
    int*    flag     = (int*)(ws + OFF_FLAG);
    int*    raystart = (int*)(ws + OFF_RSTART);

    // zero cursor + starts + bsums + flag in one async memset
    hipMemsetAsync(ws + OFF_CURSOR, 0, (OFF_FLAG + 64) - OFF_CURSOR, stream);

    count_bounds_rank<<<(N_SAMP + 255) / 256, 256, 0, stream>>>(
        tenso_id, ray_id, cursor, rank, raystart);
    scan_fused<<<NB_SCAN, 256, 0, stream>>>(cursor, starts, bsums, flag);
    build_sorted<<<(N_SAMP + 255) / 256, 256, 0, stream>>>(
        tenso_id, rank, starts, gis, gil, gws, gwl, sorted);
    gather_phase<<<(P_TENSO + 3) / 4, 256, 0, stream>>>(
        trivecs, densities, colors, starts, cursor, sorted, (float*)results);
    ray_render<<<(N_RAYS + 255) / 256, 256, 0, stream>>>(
        results, t_min, bg, raystart, step_id, out);
}

// Round 2
// 278.875 us; speedup vs baseline: 1.0649x; 1.0649x over previous
//
#include <hip/hip_runtime.h>
#include <math.h>

#define HN       250
#define WN       400
#define N_RAYS   (HN * WN)        // 100000
#define N_SAMP   1000000
#define P_TENSO  50000
#define STEP_SZ  0.005f
#define DENS_SCALE 1.0f           // min(1/(1-0), 25) = 1
#define NB_SCAN  ((P_TENSO + 1023) / 1024)   // 49

// NOTE (R7): cooperative grid.sync() measured ~100 us/sync on MI355X — do not
// re-fuse with cooperative launch. NOTE (R8): each device-scope returning
// atomicAdd costs a 64B line transaction (1M atomics == 64 MB WRITE_SIZE).
// NOTE (R9/R10 measurements): gather_phase is LATENCY-bound, not BW-bound —
// coalesced vs random reads made zero difference (55us either way), and it
// absorbs 32MB of scattered result stores for free. Scattered 32B stores in a
// thin kernel (build_sorted) cost ~14us. => Put random loads AND scatter
// stores inside gather; keep thin kernels coalesced-write-only.

// ---------------- workspace layout (bytes) ----------------
#define OFF_PACK    0            // 1M x 32B sample structs, original (n) order
#define OFF_RESULTS 32000000     // 1M x 16B (lt,r,g,b), ORIGINAL (n) order
#define OFF_PERM    48000000     // 1M int, pos -> n
#define OFF_RANK    52000000     // 1M int, rank within tid
#define OFF_CURSOR  56000000     // 50K int (atomic counters == final counts)
#define OFF_STARTS  56200000     // 50K int
#define OFF_BSUMS   56400000     // 64 int
#define OFF_FLAG    56400512     // 1 int (spin-barrier arrival)
#define OFF_RSTART  56401024     // (N_RAYS+1) int
#define WS_NEED     (56401024 + 400004 + 64)

// gather slab layout (floats), per wave
#define ROW_STRIDE 20                 // 16 ch + 4 pad
#define TV_F   (24 * ROW_STRIDE)      // 480
#define SLAB_F (TV_F + 16 + 48)       // 544

// ---------------------------------------------------------------------------
// A: pack (coalesced 32B W) + ray bounds + rank via ONE returning atomic pass
// ---------------------------------------------------------------------------
__global__ __launch_bounds__(256) void pack_bounds_rank(
    const int*   __restrict__ tenso_id,
    const int*   __restrict__ ray_id,     // sorted
    const int*   __restrict__ gis, const int* __restrict__ gil,
    const float* __restrict__ gws, const float* __restrict__ gwl,
    int* __restrict__ cursor,             // zeroed; becomes counts
    int* __restrict__ rank,
    int* __restrict__ ray_start,
    float4* __restrict__ pack)
{
    int n = blockIdx.x * 256 + threadIdx.x;
    if (n >= N_SAMP) return;

    const int tid = tenso_id[n];
    rank[n] = atomicAdd(&cursor[tid], 1);          // the single atomic pass

    unsigned bits = (unsigned)gis[n*3+0] | ((unsigned)gis[n*3+1] << 3) | ((unsigned)gis[n*3+2] << 6)
                  | ((unsigned)gil[n*3+0] << 9) | ((unsigned)gil[n*3+1] << 12) | ((unsigned)gil[n*3+2] << 15);
    float4 A = make_float4(gws[n*3+0], gws[n*3+1], gws[n*3+2], gwl[n*3+0]);
    float4 B = make_float4(gwl[n*3+1], gwl[n*3+2], __uint_as_float(bits), 0.0f);
    pack[(size_t)n * 2 + 0] = A;
    pack[(size_t)n * 2 + 1] = B;

    int r = ray_id[n];
    int rprev = (n == 0) ? -1 : ray_id[n - 1];
    for (int q = rprev + 1; q <= r; ++q) ray_start[q] = n;
    if (n == N_SAMP - 1) {
        for (int q = r + 1; q <= N_RAYS; ++q) ray_start[q] = N_SAMP;
    }
}

// ---------------------------------------------------------------------------
// B: fused exclusive scan of counts -> starts. 49 blocks (co-resident on 256
// CUs), internal spin barrier on an arrival counter.
// ---------------------------------------------------------------------------
__global__ __launch_bounds__(256) void scan_fused(
    const int* __restrict__ cursor,   // counts
    int* __restrict__ starts,
    int* __restrict__ bsums,
    int* __restrict__ flag)
{
    __shared__ int lds[257];
    const int b = blockIdx.x;
    const int t = threadIdx.x;
    const int base = b * 1024 + t * 4;

    int v[4]; int s = 0;
    #pragma unroll
    for (int i = 0; i < 4; ++i) {
        int idx = base + i;
        v[i] = (idx < P_TENSO) ? cursor[idx] : 0;
        s += v[i];
    }
    lds[t] = s;
    __syncthreads();
    for (int d = 1; d < 256; d <<= 1) {
        int x = (t >= d) ? lds[t - d] : 0;
        __syncthreads();
        lds[t] += x;
        __syncthreads();
    }
    if (t == 255) bsums[b] = lds[255];

    // ---- barrier across the 49 blocks ----
    __threadfence();
    __syncthreads();
    if (t == 0) {
        atomicAdd(flag, 1);
        while (atomicAdd(flag, 0) < gridDim.x) { }
    }
    __syncthreads();
    __threadfence();

    // every block computes its global prefix = sum of bsums[0..b)
    if (t < 64) {
        int x = (t < b) ? bsums[t] : 0;
        #pragma unroll
        for (int m = 1; m < 64; m <<= 1) x += __shfl_xor(x, m);
        if (t == 0) lds[256] = x;
    }
    __syncthreads();
    const int pre = lds[256];

    int run = pre + ((t > 0) ? lds[t - 1] : 0);
    #pragma unroll
    for (int i = 0; i < 4; ++i) {
        int idx = base + i;
        if (idx < P_TENSO) starts[idx] = run;
        run += v[i];
    }
}

// ---------------------------------------------------------------------------
// C: positions without atomics: pos = starts[tid] + rank[n]. perm only
// (iperm eliminated — ray_render streams in n order).
// ---------------------------------------------------------------------------
__global__ __launch_bounds__(256) void finalize_perm(
    const int* __restrict__ tenso_id,
    const int* __restrict__ rank,
    const int* __restrict__ starts,
    int* __restrict__ perm)
{
    int n = blockIdx.x * 256 + threadIdx.x;
    if (n >= N_SAMP) return;
    int pos = starts[tenso_id[n]] + rank[n];
    perm[pos] = n;           // random 4B into 4MB (L2-resident)
}

// ---------------------------------------------------------------------------
// Gather: one wave per tensoRF id; lanes = 16 samples x 4 channel-groups.
// R10: 2x sample unroll (32 samples/trip) — avg cnt≈20 means most waves do
// ONE trip; per-wave serial chain shrinks and the two samples' chains overlap
// (ILP). Reads perm->pack (random, measured-free); scatter-writes results to
// ORIGINAL n order (measured-free) so ray_render streams.
// ---------------------------------------------------------------------------
__global__ __launch_bounds__(256) void gather_phase(
    const float* __restrict__ trivecs,   // (P,16,3,8)
    const float* __restrict__ densities, // (P,16)
    const float* __restrict__ colors,    // (P,16,3)
    const int*   __restrict__ starts,
    const int*   __restrict__ counts,    // == cursor
    const int*   __restrict__ perm,
    const float4* __restrict__ pack,
    float* __restrict__ results_f)       // [n*4 + j], original order
{
    __shared__ __align__(16) float lds[4 * SLAB_F];
    const int lane = threadIdx.x & 63;
    const int wv   = threadIdx.x >> 6;
    const int t    = blockIdx.x * 4 + wv;
    if (t >= P_TENSO) return;

    const int start = starts[t];
    const int cnt   = counts[t];
    if (cnt == 0) return;

    float* slab = lds + wv * SLAB_F;
    float* dl   = slab + TV_F;
    float* cl   = dl + 16;

    const int g = lane >> 2;   // sample slot 0..15
    const int j = lane & 3;    // channel group
    const int end = start + cnt;

    // trip-0 perm loads issued before staging (fly under the slab loads)
    int p0 = start + g;
    int p1 = p0 + 16;
    int n0 = perm[(p0 < end) ? p0 : (end - 1)];
    int n1 = perm[(p1 < end) ? p1 : (end - 1)];

    const float* tvg = trivecs + (size_t)t * 384;
    #pragma unroll
    for (int i = 0; i < 6; ++i) {
        int l = lane + i * 64;
        int c = l / 24;
        int rem = l - c * 24;
        slab[rem * ROW_STRIDE + c] = tvg[l];
    }
    if (lane < 16) dl[lane] = densities[(size_t)t * 16 + lane];
    if (lane < 48) {
        int c = lane / 3, k = lane - c * 3;
        cl[k * 16 + c] = colors[(size_t)t * 48 + lane];
    }

    const float4 dens4 = *(const float4*)(dl + 4 * j);
    const float4 col0  = *(const float4*)(cl + 4 * j);
    const float4 col1  = *(const float4*)(cl + 16 + 4 * j);
    const float4 col2  = *(const float4*)(cl + 32 + 4 * j);

    const int niter = (cnt + 31) >> 5;   // 32 samples per trip

    for (int it = 0; it < niter; ++it) {
        const bool v0 = (p0 < end);
        const bool v1 = (p1 < end);
        const int sn0 = n0, sn1 = n1;    // saved for the stores

        const float4 A0 = pack[(size_t)sn0 * 2 + 0];
        const float4 B0 = pack[(size_t)sn0 * 2 + 1];
        const float4 A1 = pack[(size_t)sn1 * 2 + 0];
        const float4 B1 = pack[(size_t)sn1 * 2 + 1];

        if (it + 1 < niter) {            // prefetch next trip's perm
            p0 = start + (it + 1) * 32 + g;
            p1 = p0 + 16;
            n0 = perm[(p0 < end) ? p0 : (end - 1)];
            n1 = perm[(p1 < end) ? p1 : (end - 1)];
        }

        const unsigned bits0 = __float_as_uint(B0.z);
        const unsigned bits1 = __float_as_uint(B1.z);

        float4 f0, f1;
        {
            const int is0 = bits0 & 7, il0 = (bits0 >> 9) & 7;
            const int is1 = bits1 & 7, il1 = (bits1 >> 9) & 7;
            const float4 vs0 = *(const float4*)(slab + is0 * ROW_STRIDE + 4 * j);
            const float4 vl0 = *(const float4*)(slab + il0 * ROW_STRIDE + 4 * j);
            const float4 vs1 = *(const float4*)(slab + is1 * ROW_STRIDE + 4 * j);
            const float4 vl1 = *(const float4*)(slab + il1 * ROW_STRIDE + 4 * j);
            f0.x = vs0.x * A0.x + vl0.x * A0.w;
            f0.y = vs0.y * A0.x + vl0.y * A0.w;
            f0.z = vs0.z * A0.x + vl0.z * A0.w;
            f0.w = vs0.w * A0.x + vl0.w * A0.w;
            f1.x = vs1.x * A1.x + vl1.x * A1.w;
            f1.y = vs1.y * A1.x + vl1.y * A1.w;
            f1.z = vs1.z * A1.x + vl1.z * A1.w;
            f1.w = vs1.w * A1.x + vl1.w * A1.w;
        }
        {
            const int is0 = (bits0 >> 3) & 7, il0 = (bits0 >> 12) & 7;
            const int is1 = (bits1 >> 3) & 7, il1 = (bits1 >> 12) & 7;
            const float4 vs0 = *(const float4*)(slab + (8 + is0) * ROW_STRIDE + 4 * j);
            const float4 vl0 = *(const float4*)(slab + (8 + il0) * ROW_STRIDE + 4 * j);
            const float4 vs1 = *(const float4*)(slab + (8 + is1) * ROW_STRIDE + 4 * j);
            const float4 vl1 = *(const float4*)(slab + (8 + il1) * ROW_STRIDE + 4 * j);
            f0.x *= vs0.x * A0.y + vl0.x * B0.x;
            f0.y *= vs0.y * A0.y + vl0.y * B0.x;
            f0.z *= vs0.z * A0.y + vl0.z * B0.x;
            f0.w *= vs0.w * A0.y + vl0.w * B0.x;
            f1.x *= vs1.x * A1.y + vl1.x * B1.x;
            f1.y *= vs1.y * A1.y + vl1.y * B1.x;
            f1.z *= vs1.z * A1.y + vl1.z * B1.x;
            f1.w *= vs1.w * A1.y + vl1.w * B1.x;
        }
        {
            const int is0 = (bits0 >> 6) & 7, il0 = (bits0 >> 15) & 7;
            const int is1 = (bits1 >> 6) & 7, il1 = (bits1 >> 15) & 7;
            const float4 vs0 = *(const float4*)(slab + (16 + is0) * ROW_STRIDE + 4 * j);
            const float4 vl0 = *(const float4*)(slab + (16 + il0) * ROW_STRIDE + 4 * j);
            const float4 vs1 = *(const float4*)(slab + (16 + is1) * ROW_STRIDE + 4 * j);
            const float4 vl1 = *(const float4*)(slab + (16 + il1) * ROW_STRIDE + 4 * j);
            f0.x *= vs0.x * A0.z + vl0.x * B0.y;
            f0.y *= vs0.y * A0.z + vl0.y * B0.y;
            f0.z *= vs0.z * A0.z + vl0.z * B0.y;
            f0.w *= vs0.w * A0.z + vl0.w * B0.y;
            f1.x *= vs1.x * A1.z + vl1.x * B1.y;
            f1.y *= vs1.y * A1.z + vl1.y * B1.y;
            f1.z *= vs1.z * A1.z + vl1.z * B1.y;
            f1.w *= vs1.w * A1.z + vl1.w * B1.y;
        }

        float s00 = f0.x * dens4.x + f0.y * dens4.y + f0.z * dens4.z + f0.w * dens4.w;
        float s01 = f0.x * col0.x  + f0.y * col0.y  + f0.z * col0.z  + f0.w * col0.w;
        float s02 = f0.x * col1.x  + f0.y * col1.y  + f0.z * col1.z  + f0.w * col1.w;
        float s03 = f0.x * col2.x  + f0.y * col2.y  + f0.z * col2.z  + f0.w * col2.w;
        float s10 = f1.x * dens4.x + f1.y * dens4.y + f1.z * dens4.z + f1.w * dens4.w;
        float s11 = f1.x * col0.x  + f1.y * col0.y  + f1.z * col0.z  + f1.w * col0.w;
        float s12 = f1.x * col1.x  + f1.y * col1.y  + f1.z * col1.z  + f1.w * col1.w;
        float s13 = f1.x * col2.x  + f1.y * col2.y  + f1.z * col2.z  + f1.w * col2.w;

        s00 += __shfl_xor(s00, 1); s00 += __shfl_xor(s00, 2);
        s01 += __shfl_xor(s01, 1); s01 += __shfl_xor(s01, 2);
        s02 += __shfl_xor(s02, 1); s02 += __shfl_xor(s02, 2);
        s03 += __shfl_xor(s03, 1); s03 += __shfl_xor(s03, 2);
        s10 += __shfl_xor(s10, 1); s10 += __shfl_xor(s10, 2);
        s11 += __shfl_xor(s11, 1); s11 += __shfl_xor(s11, 2);
        s12 += __shfl_xor(s12, 1); s12 += __shfl_xor(s12, 2);
        s13 += __shfl_xor(s13, 1); s13 += __shfl_xor(s13, 2);

        const float sj0 = (j == 0) ? s00 : (j == 1) ? s01 : (j == 2) ? s02 : s03;
        const float sj1 = (j == 0) ? s10 : (j == 1) ? s11 : (j == 2) ? s12 : s13;
        float val0, val1;
        if (j == 0) {
            float d0 = fmaxf(sj0, 0.0f) + __logf(1.0f + __expf(-fabsf(sj0)));
            float d1 = fmaxf(sj1, 0.0f) + __logf(1.0f + __expf(-fabsf(sj1)));
            val0 = -(d0 * DENS_SCALE) * STEP_SZ;             // lt
            val1 = -(d1 * DENS_SCALE) * STEP_SZ;
        } else {
            val0 = 1.0f / (1.0f + __expf(-sj0));             // sigmoid
            val1 = 1.0f / (1.0f + __expf(-sj1));
        }
        if (v0) results_f[(size_t)sn0 * 4 + j] = val0;       // 16B-granule scatter
        if (v1) results_f[(size_t)sn1 * 4 + j] = val1;
    }
}

// ---------------------------------------------------------------------------
// E: one thread per ray; streaming loads (results in n order), telescoped
// transmittance: w = eT_prev - eT_next, ONE exp per sample instead of two.
// ---------------------------------------------------------------------------
__global__ __launch_bounds__(256) void ray_render(
    const float4* __restrict__ results,
    const float*  __restrict__ t_min,
    const float*  __restrict__ bg,
    const int*    __restrict__ ray_start,
    const int*    __restrict__ step_id,
    float* __restrict__ out)
{
    int r = blockIdx.x * 256 + threadIdx.x;
    if (r >= N_RAYS) return;
    const int s = ray_start[r];
    const int e = ray_start[r + 1];
    const float tmin_r = t_min[r];

    float eT = 1.0f, aR = 0.0f, aG = 0.0f, aB = 0.0f, aD = 0.0f;
    for (int n = s; n < e; ++n) {
        float4 res = results[n];
        const float eTn = eT * __expf(res.x);
        const float w = eT - eTn;
        eT = eTn;
        const float z = tmin_r + (float)step_id[n] * STEP_SZ;
        aR += w * res.y;
        aG += w * res.z;
        aB += w * res.w;
        aD += w * z;
    }
    out[0 * N_RAYS + r] = aR + eT * bg[0];
    out[1 * N_RAYS + r] = aG + eT * bg[1];
    out[2 * N_RAYS + r] = aB + eT * bg[2];
    out[3 * N_RAYS + r] = aD;
    out[4 * N_RAYS + r] = 1.0f - eT;
}

// ---------------------------------------------------------------------------
// Fallback (ws too small): single fused kernel, original layouts.
// ---------------------------------------------------------------------------
__global__ __launch_bounds__(256) void trivec_render_fallback(
    const float* __restrict__ trivecs, const float* __restrict__ densities,
    const float* __restrict__ colors, const float* __restrict__ gws,
    const float* __restrict__ gwl, const float* __restrict__ t_min,
    const float* __restrict__ bg, const int* __restrict__ gis,
    const int* __restrict__ gil, const int* __restrict__ tenso_id,
    const int* __restrict__ ray_id, const int* __restrict__ step_id,
    float* __restrict__ out)
{
    const int lane = threadIdx.x & 63;
    const int r = blockIdx.x * 4 + (threadIdx.x >> 6);
    if (r >= N_RAYS) return;
    const int c = lane & 15;
    const int g = lane >> 4;
    int lo = 0, hi = N_SAMP;
    while (lo < hi) { int mid = (lo + hi) >> 1; if (ray_id[mid] < r) lo = mid + 1; else hi = mid; }
    const int seg_start = lo;
    hi = N_SAMP;
    while (lo < hi) { int mid = (lo + hi) >> 1; if (ray_id[mid] < r + 1) lo = mid + 1; else hi = mid; }
    const int seg_end = lo;
    const float tmin_r = t_min[r];
    float Tlog = 0.0f, accR = 0.0f, accG = 0.0f, accB = 0.0f, accD = 0.0f;
    const int niter = (seg_end - seg_start + 3) >> 2;
    for (int it = 0; it < niter; ++it) {
        const int n = seg_start + it * 4 + g;
        const bool valid = (n < seg_end);
        const int nc = valid ? n : (seg_end - 1);
        const int tid = tenso_id[nc];
        const float* tv = trivecs + (size_t)tid * 384 + c * 24;
        float f = 1.0f;
        #pragma unroll
        for (int a = 0; a < 3; ++a) {
            const int is = gis[nc*3+a], il = gil[nc*3+a];
            const float wS = gws[nc*3+a], wL = gwl[nc*3+a];
            f *= (tv[a*8+is] * wS + tv[a*8+il] * wL);
        }
        const float dns = densities[(size_t)tid * 16 + c];
        const float* colp = colors + ((size_t)tid * 16 + c) * 3;
        float s0 = f*dns, s1 = f*colp[0], s2 = f*colp[1], s3 = f*colp[2];
        #pragma unroll
        for (int m = 1; m < 16; m <<= 1) {
            s0 += __shfl_xor(s0, m); s1 += __shfl_xor(s1, m);
            s2 += __shfl_xor(s2, m); s3 += __shfl_xor(s3, m);
        }
        float dens = fmaxf(s0, 0.0f) + __logf(1.0f + __expf(-fabsf(s0)));
        const float lt = valid ? (-dens * STEP_SZ) : 0.0f;
        const float alpha = 1.0f - __expf(lt);
        const float rr = 1.0f/(1.0f+__expf(-s1)), gg = 1.0f/(1.0f+__expf(-s2)), bb = 1.0f/(1.0f+__expf(-s3));
        const float z = tmin_r + (float)step_id[nc] * STEP_SZ;
        const float lt0 = __shfl(lt,0), lt1 = __shfl(lt,16), lt2 = __shfl(lt,32), lt3 = __shfl(lt,48);
        float excl = Tlog;
        if (g > 0) excl += lt0;
        if (g > 1) excl += lt1;
        if (g > 2) excl += lt2;
        const float w = alpha * __expf(excl);
        Tlog += lt0 + lt1 + lt2 + lt3;
        accR += w*rr; accG += w*gg; accB += w*bb; accD += w*z;
    }
    accR += __shfl_xor(accR,16); accR += __shfl_xor(accR,32);
    accG += __shfl_xor(accG,16); accG += __shfl_xor(accG,32);
    accB += __shfl_xor(accB,16); accB += __shfl_xor(accB,32);
    accD += __shfl_xor(accD,16); accD += __shfl_xor(accD,32);
    const float bgw = __expf(Tlog);
    if (lane == 0) {
        out[0*N_RAYS+r] = accR + bgw*bg[0];
        out[1*N_RAYS+r] = accG + bgw*bg[1];
        out[2*N_RAYS+r] = accB + bgw*bg[2];
        out[3*N_RAYS+r] = accD;
        out[4*N_RAYS+r] = 1.0f - bgw;
    }
}

extern "C" void kernel_launch(void* const* d_in, const int* in_sizes, int n_in,
                              void* d_out, int out_size, void* d_ws, size_t ws_size,
                              hipStream_t stream) {
    const float* trivecs   = (const float*)d_in[0];
    const float* densities = (const float*)d_in[1];
    const float* colors    = (const float*)d_in[2];
    const float* gws       = (const float*)d_in[3];
    const float* gwl       = (const float*)d_in[4];
    const float* t_min     = (const float*)d_in[5];
    const float* bg        = (const float*)d_in[6];
    const int*   gis       = (const int*)d_in[7];
    const int*   gil       = (const int*)d_in[8];
    const int*   tenso_id  = (const int*)d_in[9];
    const int*   ray_id    = (const int*)d_in[10];
    const int*   step_id   = (const int*)d_in[11];
    float* out = (float*)d_out;

    if (ws_size < (size_t)WS_NEED) {
        trivec_render_fallback<<<(N_RAYS + 3) / 4, 256, 0, stream>>>(
            trivecs, densities, colors, gws, gwl, t_min, bg,
            gis, gil, tenso_id, ray_id, step_id, out);
        return;
    }

    char* ws = (char*)d_ws;
    float4* pack     = (float4*)(ws + OFF_PACK);
    float4* results  = (float4*)(ws + OFF_RESULTS);
    int*    perm     = (int*)(ws + OFF_PERM);
    int*    rank     = (int*)(ws + OFF_RANK);
    int*    cursor   = (int*)(ws + OFF_CURSOR);
    int*    starts   = (int*)(ws + OFF_STARTS);
    int*    bsums    = (int*)(ws + OFF_BSUMS);
    int*    flag     = (int*)(ws + OFF_FLAG);
    int*    raystart = (int*)(ws + OFF_RSTART);

    // zero cursor + starts + bsums + flag in one async memset
    hipMemsetAsync(ws + OFF_CURSOR, 0, (OFF_FLAG + 64) - OFF_CURSOR, stream);

    pack_bounds_rank<<<(N_SAMP + 255) / 256, 256, 0, stream>>>(
        tenso_id, ray_id, gis, gil, gws, gwl, cursor, rank, raystart, pack);
    scan_fused<<<NB_SCAN, 256, 0, stream>>>(cursor, starts, bsums, flag);
    finalize_perm<<<(N_SAMP + 255) / 256, 256, 0, stream>>>(
        tenso_id, rank, starts, perm);
    gather_phase<<<(P_TENSO + 3) / 4, 256, 0, stream>>>(
        trivecs, densities, colors, starts, cursor, perm, pack, (float*)results);
    ray_render<<<(N_RAYS + 255) / 256, 256, 0, stream>>>(
        results, t_min, bg, raystart, step_id, out);
}